// Round 3
// baseline (9893.816 us; speedup 1.0000x reference)
//
#include <hip/hip_runtime.h>
#include <hip/hip_bf16.h>
#include <math.h>

// Problem dims
#define BATCH 256
#define SEQ   512
#define IN_D  512
#define HID   512
#define FOURH 2048
#define BS_ROWS (BATCH * SEQ)   // 131072

typedef __bf16 bf16x8 __attribute__((ext_vector_type(8)));
typedef float  f32x4  __attribute__((ext_vector_type(4)));

__device__ __forceinline__ float sigf(float x)  { return 1.0f / (1.0f + __expf(-x)); }
__device__ __forceinline__ float tanhf_(float x){ return 1.0f - 2.0f / (__expf(2.0f * x) + 1.0f); }

// ---------------------------------------------------------------------------
// Init: convert weights to bf16, fuse biases, zero h/c ping-pong bufs + flags.
// ---------------------------------------------------------------------------
__global__ __launch_bounds__(256) void init_kernel(
    const float* __restrict__ W_all_w, const float* __restrict__ W_all_b,
    const float* __restrict__ U_all_w, const float* __restrict__ U_all_b,
    const float* __restrict__ W_d_w,
    __bf16* __restrict__ Wb, __bf16* __restrict__ Ub, __bf16* __restrict__ Db,
    float* __restrict__ bias_all,
    __bf16* __restrict__ h0, __bf16* __restrict__ c0,
    unsigned* __restrict__ bar)
{
    const int stride = gridDim.x * blockDim.x;
    const int tid0 = blockIdx.x * blockDim.x + threadIdx.x;

    const int nW = FOURH * HID;
    for (int i = tid0; i < nW; i += stride) {
        Wb[i] = (__bf16)W_all_w[i];
        Ub[i] = (__bf16)U_all_w[i];
    }
    const int nD = HID * HID;
    for (int i = tid0; i < nD; i += stride) Db[i] = (__bf16)W_d_w[i];
    for (int i = tid0; i < FOURH; i += stride) bias_all[i] = W_all_b[i] + U_all_b[i];
    const int nS = BATCH * HID;
    for (int i = tid0; i < nS; i += stride) {
        h0[i] = (__bf16)0.0f;
        c0[i] = (__bf16)0.0f;
    }
    for (int i = tid0; i < 256 * 32; i += stride) bar[i] = 0u;
}

// ---------------------------------------------------------------------------
// u_proj GEMM: up[B*S, 2048] = x[B*S, 512] @ U_all^T (bf16 out, no bias).
// 128x128 tile, 256 threads (4 waves, each 64x64), BK=64, K=512.
// ---------------------------------------------------------------------------
__global__ __launch_bounds__(256) void uproj_gemm(
    const float* __restrict__ x, const __bf16* __restrict__ Ub,
    __bf16* __restrict__ up)
{
    const unsigned bid = blockIdx.x;
    const unsigned lg = (bid & 7) * 2048u + (bid >> 3);   // XCD-chunked, bijective
    const int cb = lg & 15;        // col tile (N=2048 / 128)
    const int rb = lg >> 4;        // row tile (131072 / 128)

    __shared__ __bf16 As[128][64];
    __shared__ __bf16 Bs[128][64];

    const int tid = threadIdx.x;
    const int wave = tid >> 6, lane = tid & 63;
    const int wm = wave >> 1, wn = wave & 1;
    const int lrow = lane & 15, kq = lane >> 4;
    const int sw = (lrow & 7) << 3;

    f32x4 acc[4][4];
    #pragma unroll
    for (int m = 0; m < 4; ++m)
        #pragma unroll
        for (int n = 0; n < 4; ++n) acc[m][n] = (f32x4){0.f, 0.f, 0.f, 0.f};

    const int srow = tid >> 1;
    const int skc  = (tid & 1) * 32;
    const int dsw  = (srow & 7) << 3;

    for (int kk = 0; kk < 512; kk += 64) {
        {
            const float* xs = x + (size_t)(rb * 128 + srow) * 512 + kk + skc;
            #pragma unroll
            for (int j = 0; j < 4; ++j) {
                float4 va = ((const float4*)xs)[2 * j];
                float4 vb = ((const float4*)xs)[2 * j + 1];
                bf16x8 pk;
                pk[0] = (__bf16)va.x; pk[1] = (__bf16)va.y;
                pk[2] = (__bf16)va.z; pk[3] = (__bf16)va.w;
                pk[4] = (__bf16)vb.x; pk[5] = (__bf16)vb.y;
                pk[6] = (__bf16)vb.z; pk[7] = (__bf16)vb.w;
                *(bf16x8*)&As[srow][(skc + j * 8) ^ dsw] = pk;
            }
            const __bf16* bsrc = Ub + (size_t)(cb * 128 + srow) * 512 + kk + skc;
            #pragma unroll
            for (int j = 0; j < 4; ++j)
                *(uint4*)&Bs[srow][(skc + j * 8) ^ dsw] = *(const uint4*)(bsrc + j * 8);
        }
        __syncthreads();

        #pragma unroll
        for (int k2 = 0; k2 < 2; ++k2) {
            const int ke = k2 * 32 + kq * 8;
            bf16x8 af[4], bfr[4];
            #pragma unroll
            for (int m = 0; m < 4; ++m)
                af[m] = *(const bf16x8*)&As[wm * 64 + m * 16 + lrow][ke ^ sw];
            #pragma unroll
            for (int n = 0; n < 4; ++n)
                bfr[n] = *(const bf16x8*)&Bs[wn * 64 + n * 16 + lrow][ke ^ sw];
            #pragma unroll
            for (int m = 0; m < 4; ++m)
                #pragma unroll
                for (int n = 0; n < 4; ++n)
                    acc[m][n] = __builtin_amdgcn_mfma_f32_16x16x32_bf16(af[m], bfr[n], acc[m][n], 0, 0, 0);
        }
        __syncthreads();
    }

    const int colL = lane & 15, r0 = (lane >> 4) * 4;
    const size_t orow0 = (size_t)rb * 128 + wm * 64;
    const int ocol0 = cb * 128 + wn * 64;
    #pragma unroll
    for (int m = 0; m < 4; ++m)
        #pragma unroll
        for (int n = 0; n < 4; ++n)
            #pragma unroll
            for (int i = 0; i < 4; ++i)
                up[(orow0 + m * 16 + r0 + i) * 2048 + ocol0 + n * 16 + colL] = (__bf16)acc[m][n][i];
}

// ---------------------------------------------------------------------------
// Persistent scan kernel. Grid 256 blocks x 640 threads (10 waves), 1 block/CU.
// Block (bg,hc): batch rows b0=bg*32..+31, hidden cols k0=hc*16..+15.
// Wave w: unit = w%5 (gates f,i,o,c~ + W_d), row-half rh = w/5.
// Weights resident in LDS for all 512 steps. h/c ping-pong via global bf16.
// u(t+1)/ts(t+1) prefetched during MFMA; o-store deferred past the flag store.
// Barrier: per-block release flags on separate 128B lines, wave0 polls.
// ---------------------------------------------------------------------------
__global__ __launch_bounds__(640) void scan_kernel(
    const __bf16* __restrict__ up,        // [B*S][2048]
    const float* __restrict__ timestamps, // [B][S]
    const __bf16* __restrict__ Wb,        // [2048][512]
    const __bf16* __restrict__ Db,        // [512][512]
    const float* __restrict__ bias_all,   // [2048]
    const float* __restrict__ Wd_b,       // [512]
    __bf16* __restrict__ h0buf, __bf16* __restrict__ h1buf,
    __bf16* __restrict__ c0buf, __bf16* __restrict__ c1buf,
    unsigned* __restrict__ bar,           // [256 blocks][32 uints pad]
    float* __restrict__ out)
{
    const int tid = threadIdx.x;
    const int bid = blockIdx.x;
    const int bg = bid & 7, hc = bid >> 3;
    const int b0 = bg * 32;
    const int k0 = hc * 16;
    const int wave = tid >> 6, lane = tid & 63;
    const int rh = (wave >= 5) ? 1 : 0;
    const int unit = wave - rh * 5;       // 0..4

    __shared__ __bf16 Bw[64][512];   // 64 KB gate weights
    __shared__ __bf16 Bd[16][512];   // 16 KB W_d rows
    __shared__ __bf16 Ah[32][512];   // 32 KB h tile
    __shared__ __bf16 Ac[32][512];   // 32 KB c tile (front 10.6 KB aliased as ex)
    __shared__ __bf16 Us[2][32][64]; //  8 KB u double buffer
    __shared__ float  Ts[2][32];     //  256 B ts double buffer
    __shared__ float  Cm[512];       //  2 KB c master (f32, persistent)
    __shared__ float  BiasW[64];
    __shared__ float  BiasD[16];

    // ---- preload weights + biases, zero c master, stage u(0)/ts(0) ----
    for (int ch = tid; ch < 4096; ch += 640) {
        const int row = ch >> 6, kc = (ch & 63) * 8;
        const int w = row >> 4, rr = row & 15;
        const __bf16* src = Wb + (size_t)(w * 512 + k0 + rr) * 512 + kc;
        *(uint4*)&Bw[row][kc ^ ((row & 7) << 3)] = *(const uint4*)src;
    }
    for (int ch = tid; ch < 1024; ch += 640) {
        const int row = ch >> 6, kc = (ch & 63) * 8;
        const __bf16* src = Db + (size_t)(k0 + row) * 512 + kc;
        *(uint4*)&Bd[row][kc ^ ((row & 7) << 3)] = *(const uint4*)src;
    }
    if (tid < 64) BiasW[tid] = bias_all[(tid >> 4) * 512 + k0 + (tid & 15)];
    else if (tid < 80) BiasD[tid - 64] = Wd_b[k0 + (tid - 64)];
    for (int e = tid; e < 512; e += 640) Cm[e] = 0.f;
    if (tid < 256) {
        const int row = tid >> 3, j = tid & 7;
        const __bf16* src = up + ((size_t)(b0 + row) * 512 + 0) * 2048
                               + (j >> 1) * 512 + k0 + (j & 1) * 8;
        *(uint4*)&Us[0][row][(j >> 1) * 16 + (j & 1) * 8] = *(const uint4*)src;
    }
    if (tid < 32) Ts[0][tid] = timestamps[(size_t)(b0 + tid) * 512 + 0];

    float* ex = (float*)&Ac[0][0];   // [5][32][17] f32 = 10880 B (aliased over Ac)

    const int lrow = lane & 15, kq = lane >> 4;
    const int sw = (lrow & 7) << 3;

    __syncthreads();

    #pragma unroll 1
    for (int t = 0; t < SEQ; ++t) {
        const int par = t & 1;
        const __bf16* hsrc = (par ? h1buf : h0buf) + b0 * 512;
        const __bf16* csrc = (par ? c1buf : c0buf) + b0 * 512;
        __bf16* hdst = (par ? h0buf : h1buf) + b0 * 512;
        __bf16* cdst = (par ? c0buf : c1buf) + b0 * 512;

        // ---- A: stage h, c (barrier-dependent; 8 loads/thread, 1 latency) ----
        if (tid < 512) {
            #pragma unroll
            for (int i = 0; i < 4; ++i) {
                const int ch = i * 512 + tid;
                const int row = ch >> 6, kc = (ch & 63) * 8;
                const int d = row * 512 + (kc ^ ((row & 7) << 3));
                uint4 hv = *(const uint4*)(hsrc + row * 512 + kc);
                uint4 cv = *(const uint4*)(csrc + row * 512 + kc);
                *(uint4*)(&Ah[0][0] + d) = hv;
                *(uint4*)(&Ac[0][0] + d) = cv;
            }
        }
        __syncthreads();

        // ---- B: prefetch u/ts(t+1) into regs; MFMA K=512 ----
        uint4 upf;
        float tpf = 0.f;
        const bool do_pf = (t + 1 < SEQ);
        if (do_pf && tid < 256) {
            const int row = tid >> 3, j = tid & 7;
            upf = *(const uint4*)(up + ((size_t)(b0 + row) * 512 + (t + 1)) * 2048
                                  + (j >> 1) * 512 + k0 + (j & 1) * 8);
        }
        if (do_pf && tid < 32) tpf = timestamps[(size_t)(b0 + tid) * 512 + (t + 1)];

        f32x4 acc = {0.f, 0.f, 0.f, 0.f};
        {
            const __bf16* Ab = ((unit == 4) ? &Ac[0][0] : &Ah[0][0]) + rh * 16 * 512;
            const __bf16* Bb = (unit == 4) ? &Bd[0][0] : &Bw[unit * 16][0];
            #pragma unroll
            for (int kk = 0; kk < 512; kk += 32) {
                const int ke = (kk + kq * 8) ^ sw;
                bf16x8 a = *(const bf16x8*)(Ab + lrow * 512 + ke);
                bf16x8 b = *(const bf16x8*)(Bb + lrow * 512 + ke);
                acc = __builtin_amdgcn_mfma_f32_16x16x32_bf16(a, b, acc, 0, 0, 0);
            }
        }
        // park prefetched u/ts in the other LDS buffer
        if (do_pf && tid < 256) {
            const int row = tid >> 3, j = tid & 7;
            *(uint4*)&Us[par ^ 1][row][(j >> 1) * 16 + (j & 1) * 8] = upf;
        }
        if (do_pf && tid < 32) Ts[par ^ 1][tid] = tpf;
        __syncthreads();   // all waves done reading Ah/Ac before ex overwrite

        // ---- C: epilogue -> ex (padded stride 17) ----
        {
            const int col = lane & 15, r0 = (lane >> 4) * 4;
            const float bias = (unit == 4) ? BiasD[col] : BiasW[unit * 16 + col];
            #pragma unroll
            for (int i = 0; i < 4; ++i)
                ex[unit * 544 + (rh * 16 + r0 + i) * 17 + col] = acc[i] + bias;
        }
        __syncthreads();

        // ---- D: gate update (block-local) ----
        float o_def = 0.f;
        if (tid < 512) {
            const int r = tid >> 4, k = tid & 15;
            const int rk = r * 17 + k;
            const float fo = ex[rk]        + (float)Us[par][r][k];
            const float io = ex[544 + rk]  + (float)Us[par][r][16 + k];
            const float oo = ex[1088 + rk] + (float)Us[par][r][32 + k];
            const float ct = ex[1632 + rk] + (float)Us[par][r][48 + k];
            const float dd = ex[2176 + rk];
            const float c_old = Cm[tid];
            const float tt = Ts[par][r];

            const float c_s1  = tanhf_(dd);
            const float c_adj = c_old - c_s1 + c_s1 * tt;
            const float f  = sigf(fo);
            const float ii = sigf(io);
            const float o  = sigf(oo);
            const float c_tmp = tanhf_(ct);
            const float c_new = f * c_adj + ii * c_tmp;
            const float h_new = o * tanhf_(c_new);

            Cm[tid] = c_new;
            hdst[r * 512 + k0 + k] = (__bf16)h_new;
            cdst[r * 512 + k0 + k] = (__bf16)c_new;
            if (t == SEQ - 1) {
                __builtin_nontemporal_store(o,
                    &out[((size_t)(b0 + r) * 512 + t) * 512 + k0 + k]);
                const size_t base = (size_t)BATCH * SEQ * HID;
                out[base + (size_t)(b0 + r) * 512 + k0 + k] = h_new;
                out[base + (size_t)BATCH * HID + (size_t)(b0 + r) * 512 + k0 + k] = c_new;
            } else {
                o_def = o;
            }
        }
        __syncthreads();   // per-wave vmcnt(0): all h/c stores in L2

        // ---- E: flag-based barrier; o-store overlaps the spin ----
        if (t < SEQ - 1) {
            if (tid == 0) {
                __threadfence();
                __hip_atomic_store(&bar[(bg * 32 + hc) * 32], (unsigned)(t + 1),
                                   __ATOMIC_RELEASE, __HIP_MEMORY_SCOPE_AGENT);
            }
            if (tid < 512) {
                const int r = tid >> 4, k = tid & 15;
                __builtin_nontemporal_store(o_def,
                    &out[((size_t)(b0 + r) * 512 + t) * 512 + k0 + k]);
            }
            if (tid < 32) {
                while (__hip_atomic_load(&bar[(bg * 32 + tid) * 32], __ATOMIC_ACQUIRE,
                                         __HIP_MEMORY_SCOPE_AGENT) < (unsigned)(t + 1))
                    __builtin_amdgcn_s_sleep(1);
            }
            __syncthreads();
        }
    }
}

// ---------------------------------------------------------------------------
extern "C" void kernel_launch(void* const* d_in, const int* in_sizes, int n_in,
                              void* d_out, int out_size, void* d_ws, size_t ws_size,
                              hipStream_t stream) {
    const float* inputs     = (const float*)d_in[0];
    const float* timestamps = (const float*)d_in[1];
    const float* W_all_w    = (const float*)d_in[2];
    const float* W_all_b    = (const float*)d_in[3];
    const float* U_all_w    = (const float*)d_in[4];
    const float* U_all_b    = (const float*)d_in[5];
    const float* W_d_w      = (const float*)d_in[6];
    const float* W_d_b      = (const float*)d_in[7];
    float* out = (float*)d_out;

    char* ws = (char*)d_ws;
    size_t off = 0;
    auto alloc = [&](size_t bytes) -> void* {
        void* p = ws + off;
        off += (bytes + 255) & ~(size_t)255;
        return p;
    };
    __bf16* Wb       = (__bf16*)alloc((size_t)FOURH * HID * 2);
    __bf16* Ub       = (__bf16*)alloc((size_t)FOURH * HID * 2);
    __bf16* Db       = (__bf16*)alloc((size_t)HID * HID * 2);
    float*  bias_all = (float*) alloc((size_t)FOURH * 4);
    __bf16* h0       = (__bf16*)alloc((size_t)BATCH * HID * 2);
    __bf16* h1       = (__bf16*)alloc((size_t)BATCH * HID * 2);
    __bf16* c0       = (__bf16*)alloc((size_t)BATCH * HID * 2);
    __bf16* c1       = (__bf16*)alloc((size_t)BATCH * HID * 2);
    unsigned* bar    = (unsigned*)alloc(256 * 32 * 4);
    __bf16* up       = (__bf16*)alloc((size_t)BS_ROWS * FOURH * 2);  // 512 MB

    hipLaunchKernelGGL(init_kernel, dim3(1024), dim3(256), 0, stream,
                       W_all_w, W_all_b, U_all_w, U_all_b, W_d_w,
                       Wb, Ub, Db, bias_all, h0, c0, bar);

    hipLaunchKernelGGL(uproj_gemm, dim3(16384), dim3(256), 0, stream,
                       inputs, Ub, up);

    void* sargs[] = {
        (void*)&up, (void*)&timestamps, (void*)&Wb, (void*)&Db,
        (void*)&bias_all, (void*)&W_d_b,
        (void*)&h0, (void*)&h1, (void*)&c0, (void*)&c1,
        (void*)&bar, (void*)&out
    };
    hipLaunchCooperativeKernel((const void*)scan_kernel, dim3(256), dim3(640),
                               sargs, 0, stream);
}

// Round 4
// 2585.293 us; speedup vs baseline: 3.8270x; 3.8270x over previous
//
#include <hip/hip_runtime.h>
#include <hip/hip_bf16.h>
#include <math.h>

// Problem dims
#define BATCH 256
#define SEQ   512
#define IN_D  512
#define HID   512
#define FOURH 2048
#define BS_ROWS (BATCH * SEQ)   // 131072

typedef __bf16 bf16x8 __attribute__((ext_vector_type(8)));
typedef float  f32x4  __attribute__((ext_vector_type(4)));
typedef unsigned long long ull;

__device__ __forceinline__ float sigf(float x)  { return 1.0f / (1.0f + __expf(-x)); }
__device__ __forceinline__ float tanhf_(float x){ return 1.0f - 2.0f / (__expf(2.0f * x) + 1.0f); }

// ---------------------------------------------------------------------------
// Init: weights -> bf16, fuse biases, zero hc exchange + flags.
// ---------------------------------------------------------------------------
__global__ __launch_bounds__(256) void init_kernel(
    const float* __restrict__ W_all_w, const float* __restrict__ W_all_b,
    const float* __restrict__ U_all_w, const float* __restrict__ U_all_b,
    const float* __restrict__ W_d_w,
    __bf16* __restrict__ Wb, __bf16* __restrict__ Ub, __bf16* __restrict__ Db,
    float* __restrict__ bias_all,
    unsigned* __restrict__ hc,            // [2][256][512] packed h|c<<16
    unsigned* __restrict__ bar)
{
    const int stride = gridDim.x * blockDim.x;
    const int tid0 = blockIdx.x * blockDim.x + threadIdx.x;

    const int nW = FOURH * HID;
    for (int i = tid0; i < nW; i += stride) {
        Wb[i] = (__bf16)W_all_w[i];
        Ub[i] = (__bf16)U_all_w[i];
    }
    const int nD = HID * HID;
    for (int i = tid0; i < nD; i += stride) Db[i] = (__bf16)W_d_w[i];
    for (int i = tid0; i < FOURH; i += stride) bias_all[i] = W_all_b[i] + U_all_b[i];
    for (int i = tid0; i < 2 * BATCH * HID; i += stride) hc[i] = 0u;
    for (int i = tid0; i < 256 * 32; i += stride) bar[i] = 0u;
}

// ---------------------------------------------------------------------------
// u_proj GEMM: up[B*S, 2048] = x[B*S, 512] @ U_all^T (bf16 out, no bias).
// ---------------------------------------------------------------------------
__global__ __launch_bounds__(256) void uproj_gemm(
    const float* __restrict__ x, const __bf16* __restrict__ Ub,
    __bf16* __restrict__ up)
{
    const unsigned bid = blockIdx.x;
    const unsigned lg = (bid & 7) * 2048u + (bid >> 3);   // XCD-chunked, bijective
    const int cb = lg & 15;
    const int rb = lg >> 4;

    __shared__ __bf16 As[128][64];
    __shared__ __bf16 Bs[128][64];

    const int tid = threadIdx.x;
    const int wave = tid >> 6, lane = tid & 63;
    const int wm = wave >> 1, wn = wave & 1;
    const int lrow = lane & 15, kq = lane >> 4;
    const int sw = (lrow & 7) << 3;

    f32x4 acc[4][4];
    #pragma unroll
    for (int m = 0; m < 4; ++m)
        #pragma unroll
        for (int n = 0; n < 4; ++n) acc[m][n] = (f32x4){0.f, 0.f, 0.f, 0.f};

    const int srow = tid >> 1;
    const int skc  = (tid & 1) * 32;
    const int dsw  = (srow & 7) << 3;

    for (int kk = 0; kk < 512; kk += 64) {
        {
            const float* xs = x + (size_t)(rb * 128 + srow) * 512 + kk + skc;
            #pragma unroll
            for (int j = 0; j < 4; ++j) {
                float4 va = ((const float4*)xs)[2 * j];
                float4 vb = ((const float4*)xs)[2 * j + 1];
                bf16x8 pk;
                pk[0] = (__bf16)va.x; pk[1] = (__bf16)va.y;
                pk[2] = (__bf16)va.z; pk[3] = (__bf16)va.w;
                pk[4] = (__bf16)vb.x; pk[5] = (__bf16)vb.y;
                pk[6] = (__bf16)vb.z; pk[7] = (__bf16)vb.w;
                *(bf16x8*)&As[srow][(skc + j * 8) ^ dsw] = pk;
            }
            const __bf16* bsrc = Ub + (size_t)(cb * 128 + srow) * 512 + kk + skc;
            #pragma unroll
            for (int j = 0; j < 4; ++j)
                *(uint4*)&Bs[srow][(skc + j * 8) ^ dsw] = *(const uint4*)(bsrc + j * 8);
        }
        __syncthreads();

        #pragma unroll
        for (int k2 = 0; k2 < 2; ++k2) {
            const int ke = k2 * 32 + kq * 8;
            bf16x8 af[4], bfr[4];
            #pragma unroll
            for (int m = 0; m < 4; ++m)
                af[m] = *(const bf16x8*)&As[wm * 64 + m * 16 + lrow][ke ^ sw];
            #pragma unroll
            for (int n = 0; n < 4; ++n)
                bfr[n] = *(const bf16x8*)&Bs[wn * 64 + n * 16 + lrow][ke ^ sw];
            #pragma unroll
            for (int m = 0; m < 4; ++m)
                #pragma unroll
                for (int n = 0; n < 4; ++n)
                    acc[m][n] = __builtin_amdgcn_mfma_f32_16x16x32_bf16(af[m], bfr[n], acc[m][n], 0, 0, 0);
        }
        __syncthreads();
    }

    const int colL = lane & 15, r0 = (lane >> 4) * 4;
    const size_t orow0 = (size_t)rb * 128 + wm * 64;
    const int ocol0 = cb * 128 + wn * 64;
    #pragma unroll
    for (int m = 0; m < 4; ++m)
        #pragma unroll
        for (int n = 0; n < 4; ++n)
            #pragma unroll
            for (int i = 0; i < 4; ++i)
                up[(orow0 + m * 16 + r0 + i) * 2048 + ocol0 + n * 16 + colL] = (__bf16)acc[m][n][i];
}

// ---------------------------------------------------------------------------
// Persistent scan. 256 blocks x 512 threads (8 waves), 1 block/CU.
// Block (bg,hc): batch rows b0=bg*32..+31, hidden cols k0=hcid*16..+15.
// Waves 0-3: gate PAIRS x K-half (B weights in 64 VGPRs, loaded once).
// Waves 4-7: W_d x K-quarter (B in 16 VGPRs).
// Cross-block h/c exchange + flags: relaxed agent-scope atomics (no fences,
// no cache maintenance); ordering via __syncthreads' vmcnt(0) drain.
// ---------------------------------------------------------------------------
__global__ __launch_bounds__(512) void scan_kernel(
    const __bf16* __restrict__ up,        // [B*S][2048]
    const float* __restrict__ timestamps, // [B][S]
    const __bf16* __restrict__ Wb,        // [2048][512]
    const __bf16* __restrict__ Db,        // [512][512]
    const float* __restrict__ bias_all,   // [2048]
    const float* __restrict__ Wd_b,       // [512]
    unsigned* __restrict__ hc,            // [2][256][512] packed h|c
    unsigned* __restrict__ bar,           // [256][32] flags (128B lines)
    float* __restrict__ out)
{
    const int tid = threadIdx.x;
    const int bid = blockIdx.x;
    const int bg = bid & 7, hcid = bid >> 3;
    const int b0 = bg * 32;
    const int k0 = hcid * 16;
    const int wave = tid >> 6, lane = tid & 63;
    const int lrow = lane & 15, kq = lane >> 4;
    const int sw = (lrow & 7) << 3;

    __shared__ __bf16 Ah[32][512];   // 32 KB h tile (swizzled)
    __shared__ __bf16 Ac[32][512];   // 32 KB c tile (swizzled)
    __shared__ float  exg[4 * 2 * 32 * 16];  // 16 KB gate partials [u][kh][r][k]
    __shared__ float  exd[4 * 32 * 16];      //  8 KB d partials [kq4][r][k]
    __shared__ __bf16 Us[2][32][64]; //  8 KB u double buffer
    __shared__ float  Ts[2][32];     //  ts double buffer
    __shared__ float  Cm[512];       //  2 KB c master (f32, persistent)
    __shared__ float  BiasW[64];
    __shared__ float  BiasD[16];

    // ---- one-time: B fragments into registers ----
    bf16x8 Bg[2][8];   // gate waves: 2 units x 8 kslices
    bf16x8 Bd[4];      // d waves: 4 kslices
    if (wave < 4) {
        const int kh = wave & 1, pb = wave >> 1;
        #pragma unroll
        for (int uu = 0; uu < 2; ++uu) {
            const int u = pb * 2 + uu;
            #pragma unroll
            for (int ks = 0; ks < 8; ++ks) {
                const int kk = kh * 256 + ks * 32 + kq * 8;
                Bg[uu][ks] = *(const bf16x8*)(Wb + (size_t)(u * 512 + k0 + lrow) * 512 + kk);
            }
        }
    } else {
        const int kq4 = wave - 4;
        #pragma unroll
        for (int ks = 0; ks < 4; ++ks) {
            const int kk = kq4 * 128 + ks * 32 + kq * 8;
            Bd[ks] = *(const bf16x8*)(Db + (size_t)(k0 + lrow) * 512 + kk);
        }
    }

    // ---- preamble: biases, Cm, u(0)/ts(0) ----
    if (tid < 64) BiasW[tid] = bias_all[(tid >> 4) * 512 + k0 + (tid & 15)];
    else if (tid < 80) BiasD[tid - 64] = Wd_b[k0 + (tid - 64)];
    Cm[tid] = 0.f;
    if (tid < 256) {
        const int row = tid >> 3, j = tid & 7;
        const __bf16* src = up + ((size_t)(b0 + row) * 512 + 0) * 2048
                               + (j >> 1) * 512 + k0 + (j & 1) * 8;
        *(uint4*)&Us[0][row][(j >> 1) * 16 + (j & 1) * 8] = *(const uint4*)src;
    }
    if (tid < 32) Ts[0][tid] = timestamps[(size_t)(b0 + tid) * 512 + 0];
    __syncthreads();

    #pragma unroll 1
    for (int t = 0; t < SEQ; ++t) {
        const int par = t & 1;

        // ---- S0: wait peers' hc(t) slices (flags >= t) ----
        if (t > 0) {
            if (tid < 32) {
                unsigned* fl = &bar[(bg * 32 + tid) * 32];
                while (__hip_atomic_load(fl, __ATOMIC_RELAXED,
                                         __HIP_MEMORY_SCOPE_AGENT) < (unsigned)t)
                    __builtin_amdgcn_s_sleep(2);
            }
            __syncthreads();
        }

        // ---- stage: gather hc tile (LLC-coherent), unpack -> Ah/Ac ----
        {
            const ull* src = (const ull*)(hc + (size_t)par * BATCH * HID + b0 * 512);
            ull v[16];
            #pragma unroll
            for (int i = 0; i < 16; ++i)
                v[i] = __hip_atomic_load(src + i * 512 + tid, __ATOMIC_RELAXED,
                                         __HIP_MEMORY_SCOPE_AGENT);
            #pragma unroll
            for (int i = 0; i < 16; ++i) {
                const int g = i * 512 + tid;
                const int row = g >> 8;
                const int cp = (g & 255) * 2;          // elem pair start
                const unsigned lo = (unsigned)v[i];
                const unsigned hi = (unsigned)(v[i] >> 32);
                const unsigned hp = (lo & 0xFFFFu) | (hi << 16);
                const unsigned cpk = (lo >> 16) | (hi & 0xFFFF0000u);
                const int d = cp ^ ((row & 7) << 3);
                *(unsigned*)&Ah[row][d] = hp;
                *(unsigned*)&Ac[row][d] = cpk;
            }
        }
        __syncthreads();  // S1

        // ---- MFMA phase (B in regs) + u/ts(t+1) prefetch ----
        uint4 upf;
        float tpf = 0.f;
        const bool do_pf = (t + 1 < SEQ);
        if (do_pf && tid >= 256) {
            const int row = (tid - 256) >> 3, j = (tid - 256) & 7;
            upf = *(const uint4*)(up + ((size_t)(b0 + row) * 512 + (t + 1)) * 2048
                                  + (j >> 1) * 512 + k0 + (j & 1) * 8);
            if (tid < 288) tpf = timestamps[(size_t)(b0 + (tid - 256)) * 512 + (t + 1)];
        }

        if (wave < 4) {
            const int kh = wave & 1, pb = wave >> 1;
            f32x4 acc[2][2];
            #pragma unroll
            for (int uu = 0; uu < 2; ++uu)
                #pragma unroll
                for (int rh = 0; rh < 2; ++rh) acc[uu][rh] = (f32x4){0.f, 0.f, 0.f, 0.f};
            #pragma unroll
            for (int ks = 0; ks < 8; ++ks) {
                const int koff = (kh * 256 + ks * 32 + kq * 8) ^ sw;
                bf16x8 a0 = *(const bf16x8*)&Ah[lrow][koff];
                bf16x8 a1 = *(const bf16x8*)&Ah[16 + lrow][koff];
                #pragma unroll
                for (int uu = 0; uu < 2; ++uu) {
                    acc[uu][0] = __builtin_amdgcn_mfma_f32_16x16x32_bf16(a0, Bg[uu][ks], acc[uu][0], 0, 0, 0);
                    acc[uu][1] = __builtin_amdgcn_mfma_f32_16x16x32_bf16(a1, Bg[uu][ks], acc[uu][1], 0, 0, 0);
                }
            }
            const int colL = lane & 15, r0 = (lane >> 4) * 4;
            #pragma unroll
            for (int uu = 0; uu < 2; ++uu)
                #pragma unroll
                for (int rh = 0; rh < 2; ++rh)
                    #pragma unroll
                    for (int i = 0; i < 4; ++i)
                        exg[(((pb * 2 + uu) * 2 + kh) * 32 + rh * 16 + r0 + i) * 16 + colL] = acc[uu][rh][i];
        } else {
            const int kq4 = wave - 4;
            f32x4 acc0 = {0.f, 0.f, 0.f, 0.f}, acc1 = {0.f, 0.f, 0.f, 0.f};
            #pragma unroll
            for (int ks = 0; ks < 4; ++ks) {
                const int koff = (kq4 * 128 + ks * 32 + kq * 8) ^ sw;
                bf16x8 a0 = *(const bf16x8*)&Ac[lrow][koff];
                bf16x8 a1 = *(const bf16x8*)&Ac[16 + lrow][koff];
                acc0 = __builtin_amdgcn_mfma_f32_16x16x32_bf16(a0, Bd[ks], acc0, 0, 0, 0);
                acc1 = __builtin_amdgcn_mfma_f32_16x16x32_bf16(a1, Bd[ks], acc1, 0, 0, 0);
            }
            const int colL = lane & 15, r0 = (lane >> 4) * 4;
            #pragma unroll
            for (int i = 0; i < 4; ++i) {
                exd[(kq4 * 32 + r0 + i) * 16 + colL]      = acc0[i];
                exd[(kq4 * 32 + 16 + r0 + i) * 16 + colL] = acc1[i];
            }
        }

        // park prefetched u/ts
        if (do_pf && tid >= 256) {
            const int row = (tid - 256) >> 3, j = (tid - 256) & 7;
            *(uint4*)&Us[par ^ 1][row][(j >> 1) * 16 + (j & 1) * 8] = upf;
            if (tid < 288) Ts[par ^ 1][tid - 256] = tpf;
        }
        __syncthreads();  // S2

        // ---- gate update ----
        float o_def = 0.f;
        {
            const int r = tid >> 4, k = tid & 15;
            float g4[4];
            #pragma unroll
            for (int g = 0; g < 4; ++g)
                g4[g] = exg[((g * 2 + 0) * 32 + r) * 16 + k]
                      + exg[((g * 2 + 1) * 32 + r) * 16 + k]
                      + (float)Us[par][r][g * 16 + k] + BiasW[g * 16 + k];
            float dd = BiasD[k];
            #pragma unroll
            for (int q = 0; q < 4; ++q) dd += exd[(q * 32 + r) * 16 + k];

            const float c_old = Cm[tid];
            const float tt = Ts[par][r];
            const float c_s1  = tanhf_(dd);
            const float c_adj = c_old - c_s1 + c_s1 * tt;
            const float f  = sigf(g4[0]);
            const float ii = sigf(g4[1]);
            const float o  = sigf(g4[2]);
            const float c_tmp = tanhf_(g4[3]);
            const float c_new = f * c_adj + ii * c_tmp;
            const float h_new = o * tanhf_(c_new);
            Cm[tid] = c_new;

            if (t == SEQ - 1) {
                __builtin_nontemporal_store(o,
                    &out[((size_t)(b0 + r) * 512 + t) * 512 + k0 + k]);
                const size_t base = (size_t)BATCH * SEQ * HID;
                out[base + (size_t)(b0 + r) * 512 + k0 + k] = h_new;
                out[base + (size_t)BATCH * HID + (size_t)(b0 + r) * 512 + k0 + k] = c_new;
            } else {
                o_def = o;
                const unsigned short hb = __builtin_bit_cast(unsigned short, (__bf16)h_new);
                const unsigned short cb = __builtin_bit_cast(unsigned short, (__bf16)c_new);
                const unsigned pk = (unsigned)hb | ((unsigned)cb << 16);
                unsigned* dst = hc + (size_t)(par ^ 1) * BATCH * HID
                                   + (size_t)(b0 + r) * 512 + k0 + k;
                __hip_atomic_store(dst, pk, __ATOMIC_RELAXED, __HIP_MEMORY_SCOPE_AGENT);
            }
        }
        __syncthreads();  // S3: vmcnt(0) -> hc stores visible at LLC

        if (t < SEQ - 1) {
            if (tid == 0)
                __hip_atomic_store(&bar[(bg * 32 + hcid) * 32], (unsigned)(t + 1),
                                   __ATOMIC_RELAXED, __HIP_MEMORY_SCOPE_AGENT);
            {
                const int r = tid >> 4, k = tid & 15;
                __builtin_nontemporal_store(o_def,
                    &out[((size_t)(b0 + r) * 512 + t) * 512 + k0 + k]);
            }
        }
    }
}

// ---------------------------------------------------------------------------
extern "C" void kernel_launch(void* const* d_in, const int* in_sizes, int n_in,
                              void* d_out, int out_size, void* d_ws, size_t ws_size,
                              hipStream_t stream) {
    const float* inputs     = (const float*)d_in[0];
    const float* timestamps = (const float*)d_in[1];
    const float* W_all_w    = (const float*)d_in[2];
    const float* W_all_b    = (const float*)d_in[3];
    const float* U_all_w    = (const float*)d_in[4];
    const float* U_all_b    = (const float*)d_in[5];
    const float* W_d_w      = (const float*)d_in[6];
    const float* W_d_b      = (const float*)d_in[7];
    float* out = (float*)d_out;

    char* ws = (char*)d_ws;
    size_t off = 0;
    auto alloc = [&](size_t bytes) -> void* {
        void* p = ws + off;
        off += (bytes + 255) & ~(size_t)255;
        return p;
    };
    __bf16* Wb       = (__bf16*)alloc((size_t)FOURH * HID * 2);
    __bf16* Ub       = (__bf16*)alloc((size_t)FOURH * HID * 2);
    __bf16* Db       = (__bf16*)alloc((size_t)HID * HID * 2);
    float*  bias_all = (float*) alloc((size_t)FOURH * 4);
    unsigned* hcbuf  = (unsigned*)alloc((size_t)2 * BATCH * HID * 4);
    unsigned* bar    = (unsigned*)alloc(256 * 32 * 4);
    __bf16* up       = (__bf16*)alloc((size_t)BS_ROWS * FOURH * 2);  // 512 MB

    hipLaunchKernelGGL(init_kernel, dim3(1024), dim3(256), 0, stream,
                       W_all_w, W_all_b, U_all_w, U_all_b, W_d_w,
                       Wb, Ub, Db, bias_all, hcbuf, bar);

    hipLaunchKernelGGL(uproj_gemm, dim3(16384), dim3(256), 0, stream,
                       inputs, Ub, up);

    void* sargs[] = {
        (void*)&up, (void*)&timestamps, (void*)&Wb, (void*)&Db,
        (void*)&bias_all, (void*)&W_d_b,
        (void*)&hcbuf, (void*)&bar, (void*)&out
    };
    hipLaunchCooperativeKernel((const void*)scan_kernel, dim3(256), dim3(512),
                               sargs, 0, stream);
}